// Round 8
// baseline (261.398 us; speedup 1.0000x reference)
//
#include <hip/hip_runtime.h>

// LabelLoss: out[b] = sum_{n,c<7} (pred[b,n,c] - gt[b,n,c])^2
// pred/gt: [256, 16384, 8] fp32.
// History: R1-R4 ~100 us (all loads allocating: ~10.5 GB/s/CU read cap).
// R6 nt loads (L1 bypass): ~75 us (~14 GB/s/CU). R7 pipeline on nt: neutral
// -> request-service rate, not MLP, is the wall.
// R8: split the streams across the two read paths. Harness restores pred
// then gt; gt (134 MB) fits L3, pred is evicted (FETCH_SIZE was exactly one
// input in R1-R5). So: pred -> nontemporal (HBM stream, no L1 alloc);
// gt -> normal cached loads (L3/L2-served, allocating path). If the two
// paths queue independently, they overlap -> ~20+ GB/s/CU.

#define THREADS 256
#define SPLIT 8                               // blocks per batch row
#define F4_PER_BATCH (16384 * 2)              // 32768 float4s per batch per input
#define F4_PER_BLOCK (F4_PER_BATCH / SPLIT)   // 4096
#define UNROLL 4
#define OUTER (F4_PER_BLOCK / (THREADS * UNROLL))  // 4

typedef float vfloat4 __attribute__((ext_vector_type(4)));

__global__ __launch_bounds__(THREADS) void label_loss_kernel(
    const vfloat4* __restrict__ pred,
    const vfloat4* __restrict__ gt,
    float* __restrict__ out)
{
    const int bx  = blockIdx.x;
    const int b   = bx / SPLIT;
    const int seg = bx % SPLIT;
    const long base = (long)b * F4_PER_BATCH + (long)seg * F4_PER_BLOCK;

    // Channel-7 mask: float4 index parity == tid&1 (all strides even):
    // lane-uniform, no divergence.
    const float m = (threadIdx.x & 1) ? 0.0f : 1.0f;

    float acc0 = 0.0f, acc1 = 0.0f, acc2 = 0.0f, acc3 = 0.0f;

    #pragma unroll 1
    for (int it = 0; it < OUTER; ++it) {
        const long i0 = base + (long)it * (THREADS * UNROLL) + threadIdx.x;
        // pred: nontemporal -> bypass L1 allocation, stream from HBM.
        const vfloat4 p0 = __builtin_nontemporal_load(&pred[i0]);
        const vfloat4 p1 = __builtin_nontemporal_load(&pred[i0 + 256]);
        const vfloat4 p2 = __builtin_nontemporal_load(&pred[i0 + 512]);
        const vfloat4 p3 = __builtin_nontemporal_load(&pred[i0 + 768]);
        // gt: normal cached loads -> served from L3 (harness-warmed).
        const vfloat4 g0 = gt[i0];
        const vfloat4 g1 = gt[i0 + 256];
        const vfloat4 g2 = gt[i0 + 512];
        const vfloat4 g3 = gt[i0 + 768];

        vfloat4 d;
        d = p0 - g0;
        acc0 += d.x * d.x + d.y * d.y + d.z * d.z + m * (d.w * d.w);
        d = p1 - g1;
        acc1 += d.x * d.x + d.y * d.y + d.z * d.z + m * (d.w * d.w);
        d = p2 - g2;
        acc2 += d.x * d.x + d.y * d.y + d.z * d.z + m * (d.w * d.w);
        d = p3 - g3;
        acc3 += d.x * d.x + d.y * d.y + d.z * d.z + m * (d.w * d.w);
    }

    float v = (acc0 + acc1) + (acc2 + acc3);

    // 64-lane wave reduction
    #pragma unroll
    for (int off = 32; off > 0; off >>= 1)
        v += __shfl_down(v, off, 64);

    __shared__ float wsum[THREADS / 64];
    const int lane = threadIdx.x & 63;
    const int wave = threadIdx.x >> 6;
    if (lane == 0) wsum[wave] = v;
    __syncthreads();

    if (threadIdx.x == 0) {
        atomicAdd(&out[b], wsum[0] + wsum[1] + wsum[2] + wsum[3]);
    }
}

extern "C" void kernel_launch(void* const* d_in, const int* in_sizes, int n_in,
                              void* d_out, int out_size, void* d_ws, size_t ws_size,
                              hipStream_t stream) {
    const vfloat4* pred = (const vfloat4*)d_in[0];
    const vfloat4* gt   = (const vfloat4*)d_in[1];
    float* out = (float*)d_out;

    // d_out is re-poisoned to 0xAA before every launch; we accumulate with
    // atomics, so zero it first (async memset is graph-capture safe).
    (void)hipMemsetAsync(d_out, 0, (size_t)out_size * sizeof(float), stream);

    const int n_blocks = 256 * SPLIT;  // 2048 blocks, 8 per CU
    label_loss_kernel<<<dim3(n_blocks), dim3(THREADS), 0, stream>>>(pred, gt, out);
}